// Round 7
// baseline (5247.218 us; speedup 1.0000x reference)
//
#include <hip/hip_runtime.h>
#include <cstdint>
#include <cstddef>

#define BB 8
#define NN 4096
#define FF 64
#define SS 2048
#define KK 64
#define H1c 64
#define H2c 64
#define H3c 128
#define R2 0.04f
#define CAP 448
#define NCONS 248  // consumer blocks; grid = 8 + 248 = 256 <= 256 CUs -> all co-resident

typedef unsigned long long ull;
typedef __attribute__((ext_vector_type(4))) float f32x4;
typedef __attribute__((ext_vector_type(8))) short bf16x8;

// Exact (numpy-order, non-fma) squared distance: (dx*dx + dy*dy) + dz*dz
__device__ __forceinline__ float d2_exact(float ax, float ay, float az,
                                          float bx, float by, float bz) {
  float dx = __fsub_rn(ax, bx);
  float dy = __fsub_rn(ay, by);
  float dz = __fsub_rn(az, bz);
  return __fadd_rn(__fadd_rn(__fmul_rn(dx, dx), __fmul_rn(dy, dy)), __fmul_rn(dz, dz));
}

// round-to-nearest-even float -> bf16 bits
__device__ __forceinline__ unsigned short f2bf(float f) {
  unsigned u = __float_as_uint(f);
  return (unsigned short)((u + 0x7fffu + ((u >> 16) & 1u)) >> 16);
}

#define WAVE_MAX_DPP(v)                                                        \
  do {                                                                         \
    v = max(v, __builtin_amdgcn_update_dpp(0, v, 0x111, 0xf, 0xf, true));      \
    v = max(v, __builtin_amdgcn_update_dpp(0, v, 0x112, 0xf, 0xf, true));      \
    v = max(v, __builtin_amdgcn_update_dpp(0, v, 0x114, 0xf, 0xf, true));      \
    v = max(v, __builtin_amdgcn_update_dpp(0, v, 0x118, 0xf, 0xf, true));      \
    v = max(v, __builtin_amdgcn_update_dpp(0, v, 0x142, 0xf, 0xf, true));      \
    v = max(v, __builtin_amdgcn_update_dpp(0, v, 0x143, 0xf, 0xf, true));      \
  } while (0)

// ---------------- Fused kernel: FPS producers (blocks 0..7) + persistent ----
// consumers (y1 pre-phase, then per-wave ball-query gated on fps progress).
// FPS publishes each centroid via device-scope atomic stores (posw) and a
// release-store progress counter; consumer waves acquire-spin then scan.
// Grid=256 blocks, <=63.5KB LDS each -> all co-resident, deadlock-free.
__global__ __launch_bounds__(256) void fused_kernel(
    const float* __restrict__ pos, const float* __restrict__ x,
    const float* __restrict__ W1, const float* __restrict__ b1,
    float* __restrict__ pos_out, float* __restrict__ batch_out,
    unsigned short* __restrict__ y1b, float* __restrict__ posw,
    int* __restrict__ prog, int* __restrict__ nbr) {
  __shared__ __align__(16) char smem[63488];
  const int tid = threadIdx.x;

  if (blockIdx.x < BB) {
    // ================= FPS role (R1-proven structure) =================
    float* plds = (float*)smem;
    ull(*skey)[4] = (ull(*)[4])(smem + 49152);
    const int b = blockIdx.x;
    const float4* src = (const float4*)(pos + (size_t)b * NN * 3);
    float4* dstl = (float4*)plds;
#pragma unroll
    for (int k = 0; k < 12; ++k) dstl[tid + k * 256] = src[tid + k * 256];
    __syncthreads();

    float px[16], py[16], pz[16], dmin[16];
#pragma unroll
    for (int i = 0; i < 16; ++i) {
      int p = tid * 16 + i;
      px[i] = plds[p * 3 + 0];
      py[i] = plds[p * 3 + 1];
      pz[i] = plds[p * 3 + 2];
      dmin[i] = INFINITY;
    }
    const int lane = tid & 63, wv = tid >> 6;
    float cx = plds[0], cy = plds[1], cz = plds[2];

    for (int s = 0; s < SS; ++s) {
      if (tid == 0) {
        int o = b * SS + s;
        pos_out[o * 3 + 0] = cx;
        pos_out[o * 3 + 1] = cy;
        pos_out[o * 3 + 2] = cz;
        __hip_atomic_store(&posw[o * 3 + 0], cx, __ATOMIC_RELAXED,
                           __HIP_MEMORY_SCOPE_AGENT);
        __hip_atomic_store(&posw[o * 3 + 1], cy, __ATOMIC_RELAXED,
                           __HIP_MEMORY_SCOPE_AGENT);
        __hip_atomic_store(&posw[o * 3 + 2], cz, __ATOMIC_RELAXED,
                           __HIP_MEMORY_SCOPE_AGENT);
        __hip_atomic_store(&prog[b], s + 1, __ATOMIC_RELEASE,
                           __HIP_MEMORY_SCOPE_AGENT);
      }
      ull kk[16];
#pragma unroll
      for (int i = 0; i < 16; ++i) {
        float d = d2_exact(px[i], py[i], pz[i], cx, cy, cz);
        dmin[i] = fminf(dmin[i], d);
        kk[i] = ((ull)__float_as_uint(dmin[i]) << 32) | (unsigned)(~(tid * 16 + i));
      }
#pragma unroll
      for (int st = 1; st < 16; st <<= 1)
#pragma unroll
        for (int i = 0; i < 16; i += 2 * st)
          if (kk[i + st] > kk[i]) kk[i] = kk[i + st];
      const ull best = kk[0];

      const int hi = (int)(unsigned)(best >> 32);
      int v = hi;
      WAVE_MAX_DPP(v);
      const int wmax = __builtin_amdgcn_readlane(v, 63);
      const ull bal = __ballot(hi == wmax);
      const int wl = (int)__builtin_ctzll(bal);
      const unsigned klo =
          (unsigned)__builtin_amdgcn_readlane((int)(unsigned)best, wl);
      const int buf = s & 1;
      if (lane == 0) skey[buf][wv] = ((ull)(unsigned)wmax << 32) | klo;
      __syncthreads();

      const ull k0 = skey[buf][0], k1 = skey[buf][1];
      const ull k2 = skey[buf][2], k3 = skey[buf][3];
      ull ka = k0 > k1 ? k0 : k1;
      const ull kb2 = k2 > k3 ? k2 : k3;
      if (kb2 > ka) ka = kb2;
      const int cur = (int)(~(unsigned)(ka & 0xffffffffu));
      cx = plds[cur * 3 + 0];
      cy = plds[cur * 3 + 1];
      cz = plds[cur * 3 + 2];
    }
    for (int i = tid; i < SS; i += 256) batch_out[b * SS + i] = (float)blockIdx.x;
    return;
  }

  // ================= Consumer role =================
  const int cid = blockIdx.x - BB;  // 0..247

  // ---- phase 1: y1 = x @ W1[0:64,:] + b1 -> bf16, tiles strided over consumers
  {
    float(*xs)[65] = (float(*)[65])smem;
    for (int t = cid; t < 512; t += NCONS) {
      const int r0 = t * 64;
      const float4* src = (const float4*)(x + (size_t)r0 * FF);
#pragma unroll
      for (int q = 0; q < 4; q++) {
        int p = tid + q * 256;
        float4 v = src[p];
        int row = (p * 4) >> 6, col = (p * 4) & 63;
        xs[row][col + 0] = v.x;
        xs[row][col + 1] = v.y;
        xs[row][col + 2] = v.z;
        xs[row][col + 3] = v.w;
      }
      __syncthreads();
      const int c4 = (tid & 15) * 4, kb = (tid >> 4) * 4;
      float acc[4][4];
#pragma unroll
      for (int kq = 0; kq < 4; kq++) {
        acc[kq][0] = b1[c4 + 0];
        acc[kq][1] = b1[c4 + 1];
        acc[kq][2] = b1[c4 + 2];
        acc[kq][3] = b1[c4 + 3];
      }
      for (int f = 0; f < FF; ++f) {
        float4 w = *(const float4*)(W1 + f * H1c + c4);
#pragma unroll
        for (int kq = 0; kq < 4; kq++) {
          float a = xs[kb + kq][f];
          acc[kq][0] += a * w.x;
          acc[kq][1] += a * w.y;
          acc[kq][2] += a * w.z;
          acc[kq][3] += a * w.w;
        }
      }
#pragma unroll
      for (int kq = 0; kq < 4; kq++) {
        ushort4 o;
        o.x = f2bf(acc[kq][0]);
        o.y = f2bf(acc[kq][1]);
        o.z = f2bf(acc[kq][2]);
        o.w = f2bf(acc[kq][3]);
        *(ushort4*)(y1b + (size_t)(r0 + kb + kq) * H1c + c4) = o;
      }
      __syncthreads();
    }
  }

  // ---- phase 2: load this consumer's cloud into LDS
  const int b = cid / 31;  // 31 consumers per cloud
  float* plds = (float*)smem;
  {
    const float4* src = (const float4*)(pos + (size_t)b * NN * 3);
    float4* dstl = (float4*)plds;
#pragma unroll
    for (int k = 0; k < 12; k++) dstl[tid + k * 256] = src[tid + k * 256];
  }
  __syncthreads();

  // ---- phase 3: per-wave independent ball-query workers, gated on progress
  const int w = tid >> 6, lane = tid & 63;
  float* md2 = (float*)(smem + 49152) + w * CAP;
  int* mix = (int*)(smem + 49152 + 4 * CAP * 4) + w * CAP;
  const int worker = (cid % 31) * 4 + w;  // 0..123 per cloud

  for (int s = worker; s < SS; s += 124) {
    const int g = b * SS + s;
    while (__hip_atomic_load(&prog[b], __ATOMIC_ACQUIRE,
                             __HIP_MEMORY_SCOPE_AGENT) <= s)
      __builtin_amdgcn_s_sleep(8);
    const float cx = __hip_atomic_load(&posw[g * 3 + 0], __ATOMIC_RELAXED,
                                       __HIP_MEMORY_SCOPE_AGENT);
    const float cy = __hip_atomic_load(&posw[g * 3 + 1], __ATOMIC_RELAXED,
                                       __HIP_MEMORY_SCOPE_AGENT);
    const float cz = __hip_atomic_load(&posw[g * 3 + 2], __ATOMIC_RELAXED,
                                       __HIP_MEMORY_SCOPE_AGENT);
    int cnt = 0;
    for (int t = 0; t < 64; ++t) {
      int j = t * 64 + lane;
      float d2 = d2_exact(plds[j * 3 + 0], plds[j * 3 + 1], plds[j * 3 + 2],
                          cx, cy, cz);
      bool pred = (d2 <= R2);
      unsigned long long mask = __ballot(pred);
      if (pred) {
        int p = cnt + __popcll(mask & ((1ull << lane) - 1ull));
        if (p < CAP) { md2[p] = d2; mix[p] = j; }
      }
      cnt += (int)__popcll(mask);
    }
    int M = cnt < CAP ? cnt : CAP;

    if (M <= 64) {
      int v = (lane < M) ? (b * NN + mix[lane]) : -1;
      nbr[(size_t)g * KK + lane] = v;
    } else {
      float ed[7];
      int ei[7];
#pragma unroll
      for (int q = 0; q < 7; q++) {
        int p = lane + q * 64;
        if (p < M) { ed[q] = md2[p]; ei[q] = mix[p]; }
        else { ed[q] = 0.f; ei[q] = -1; }
      }
      for (int it = 0; it < KK; ++it) {
        unsigned long long key = ~0ull;
#pragma unroll
        for (int q = 0; q < 7; q++) {
          if (ei[q] >= 0) {
            unsigned long long k2 =
                ((unsigned long long)__float_as_uint(ed[q]) << 32) | (unsigned)ei[q];
            if (k2 < key) key = k2;
          }
        }
#pragma unroll
        for (int off = 32; off; off >>= 1) {
          unsigned long long ok = __shfl_xor(key, off);
          if (ok < key) key = ok;
        }
        int widx = (int)(key & 0xffffffffull);
        if (lane == it) nbr[(size_t)g * KK + it] = b * NN + widx;
#pragma unroll
        for (int q = 0; q < 7; q++) {
          if (ei[q] == widx) ei[q] = -1;
        }
      }
    }
  }
}

// ---------------- prep: pack W2/W3 into bf16 MFMA B-fragment order ----------
__global__ __launch_bounds__(256) void prep_kernel(const float* __restrict__ W2,
                                                   const float* __restrict__ W3,
                                                   unsigned short* __restrict__ w2p,
                                                   unsigned short* __restrict__ w3p) {
  const int tid = threadIdx.x;
  for (int e = tid; e < 4096; e += 256) {
    int j = e & 7, l = (e >> 3) & 63, s = (e >> 9) & 1, c = e >> 10;
    w2p[e] = f2bf(W2[(s * 32 + 8 * (l >> 4) + j) * H2c + c * 16 + (l & 15)]);
  }
  for (int e = tid; e < 8192; e += 256) {
    int j = e & 7, l = (e >> 3) & 63, s = (e >> 9) & 1, c = e >> 10;
    w3p[e] = f2bf(W3[(s * 32 + 8 * (l >> 4) + j) * H3c + c * 16 + (l & 15)]);
  }
}

// ---------------- MFMA MLP (bf16 in, fp32 accum) + max aggregation ----------
__global__ __launch_bounds__(256) void mlp_kernel(
    const float* __restrict__ pos, const unsigned short* __restrict__ y1b,
    const float* __restrict__ W1, const float* __restrict__ b2,
    const float* __restrict__ b3, const unsigned short* __restrict__ w2p,
    const unsigned short* __restrict__ w3p, const int* __restrict__ nbr,
    const float* __restrict__ pos_out, float* __restrict__ x_out) {
  __shared__ __align__(16) unsigned short lw2[4096];
  __shared__ __align__(16) unsigned short lw3[8192];
  __shared__ float w1r[3][64];
  __shared__ int nl[64];
  __shared__ float red[4][128];
  __shared__ __align__(16) unsigned short h2t[4][16][88];
  const int g = blockIdx.x;
  const int tid = threadIdx.x;

  {
    const uint4* s2 = (const uint4*)w2p;
    uint4* d2v = (uint4*)lw2;
    for (int i = tid; i < 512; i += 256) d2v[i] = s2[i];
    const uint4* s3 = (const uint4*)w3p;
    uint4* d3v = (uint4*)lw3;
    for (int i = tid; i < 1024; i += 256) d3v[i] = s3[i];
    if (tid < 192) w1r[tid / 64][tid % 64] = W1[(64 + tid / 64) * H1c + (tid % 64)];
    if (tid < 64) nl[tid] = nbr[(size_t)g * KK + tid];
  }
  const float cx = pos_out[g * 3 + 0], cy = pos_out[g * 3 + 1], cz = pos_out[g * 3 + 2];
  __syncthreads();

  const int lane = tid & 63, wv = tid >> 6;
  const int lrow = lane & 15, g16 = lane >> 4;
  const int r = wv * 16 + lrow;
  const int j = nl[r];

  bf16x8 a0 = (bf16x8)0, a1 = (bf16x8)0;
  if (j >= 0) {
    const float rx = pos[j * 3 + 0] - cx;
    const float ry = pos[j * 3 + 1] - cy;
    const float rz = pos[j * 3 + 2] - cz;
    const unsigned short* yr = y1b + (size_t)j * H1c;
    uint4 vlo = *(const uint4*)(yr + 8 * g16);
    uint4 vhi = *(const uint4*)(yr + 32 + 8 * g16);
    const unsigned* plo = (const unsigned*)&vlo;
    const unsigned* phi = (const unsigned*)&vhi;
#pragma unroll
    for (int q = 0; q < 4; ++q) {
      unsigned u = plo[q];
      int k0 = 8 * g16 + 2 * q;
      float e0 = __uint_as_float(u << 16) + rx * w1r[0][k0] + ry * w1r[1][k0] +
                 rz * w1r[2][k0];
      float e1 = __uint_as_float(u & 0xffff0000u) + rx * w1r[0][k0 + 1] +
                 ry * w1r[1][k0 + 1] + rz * w1r[2][k0 + 1];
      a0[2 * q] = (short)f2bf(fmaxf(e0, 0.f));
      a0[2 * q + 1] = (short)f2bf(fmaxf(e1, 0.f));
      unsigned u2 = phi[q];
      int k1 = 32 + k0;
      float f0 = __uint_as_float(u2 << 16) + rx * w1r[0][k1] + ry * w1r[1][k1] +
                 rz * w1r[2][k1];
      float f1 = __uint_as_float(u2 & 0xffff0000u) + rx * w1r[0][k1 + 1] +
                 ry * w1r[1][k1 + 1] + rz * w1r[2][k1 + 1];
      a1[2 * q] = (short)f2bf(fmaxf(f0, 0.f));
      a1[2 * q + 1] = (short)f2bf(fmaxf(f1, 0.f));
    }
  }

  const bf16x8* w2f = (const bf16x8*)lw2;
  const bf16x8* w3f = (const bf16x8*)lw3;
#pragma unroll
  for (int c = 0; c < 4; ++c) {
    float bb = b2[c * 16 + lrow];
    f32x4 acc = {bb, bb, bb, bb};
    acc = __builtin_amdgcn_mfma_f32_16x16x32_bf16(a0, w2f[(c * 2 + 0) * 64 + lane], acc, 0, 0, 0);
    acc = __builtin_amdgcn_mfma_f32_16x16x32_bf16(a1, w2f[(c * 2 + 1) * 64 + lane], acc, 0, 0, 0);
#pragma unroll
    for (int t = 0; t < 4; ++t)
      h2t[wv][4 * g16 + t][c * 16 + lrow] = f2bf(fmaxf(acc[t], 0.f));
  }

  bf16x8 a20 = *(const bf16x8*)&h2t[wv][lrow][8 * g16];
  bf16x8 a21 = *(const bf16x8*)&h2t[wv][lrow][32 + 8 * g16];

  float vmax[8];
#pragma unroll
  for (int c = 0; c < 8; ++c) {
    float bb = b3[c * 16 + lrow];
    f32x4 acc = {bb, bb, bb, bb};
    acc = __builtin_amdgcn_mfma_f32_16x16x32_bf16(a20, w3f[(c * 2 + 0) * 64 + lane], acc, 0, 0, 0);
    acc = __builtin_amdgcn_mfma_f32_16x16x32_bf16(a21, w3f[(c * 2 + 1) * 64 + lane], acc, 0, 0, 0);
    float m = -INFINITY;
#pragma unroll
    for (int t = 0; t < 4; ++t) {
      int rg = wv * 16 + 4 * g16 + t;
      float val = (nl[rg] >= 0) ? fmaxf(acc[t], 0.f) : -INFINITY;
      m = fmaxf(m, val);
    }
    m = fmaxf(m, __shfl_xor(m, 16));
    m = fmaxf(m, __shfl_xor(m, 32));
    vmax[c] = m;
  }
  if (g16 == 0) {
#pragma unroll
    for (int c = 0; c < 8; ++c) red[wv][c * 16 + lrow] = vmax[c];
  }
  __syncthreads();
  if (tid < H3c) {
    float m = fmaxf(fmaxf(red[0][tid], red[1][tid]), fmaxf(red[2][tid], red[3][tid]));
    x_out[(size_t)g * H3c + tid] = m;
  }
}

extern "C" void kernel_launch(void* const* d_in, const int* in_sizes, int n_in,
                              void* d_out, int out_size, void* d_ws, size_t ws_size,
                              hipStream_t stream) {
  const float* x = (const float*)d_in[0];
  const float* pos = (const float*)d_in[1];
  // d_in[2] = batch (int32) unused: clouds are equal-size by construction
  const float* W1 = (const float*)d_in[3];
  const float* b1 = (const float*)d_in[4];
  const float* W2 = (const float*)d_in[5];
  const float* b2 = (const float*)d_in[6];
  const float* W3 = (const float*)d_in[7];
  const float* b3 = (const float*)d_in[8];

  float* out = (float*)d_out;
  float* x_out = out;                                // [B*S, 128]
  float* pos_out = out + (size_t)BB * SS * H3c;      // [B*S, 3]
  float* batch_out = pos_out + (size_t)BB * SS * 3;  // [B*S]

  // workspace layout
  const size_t y1_bytes = (size_t)BB * NN * H1c * sizeof(unsigned short);  // 4 MB
  const size_t nbr_bytes = (size_t)BB * SS * KK * sizeof(int);             // 4 MB
  const size_t w2p_bytes = 4096 * sizeof(unsigned short);
  const size_t w3p_bytes = 8192 * sizeof(unsigned short);
  const size_t posw_bytes = (size_t)BB * SS * 3 * sizeof(float);
  const size_t need =
      y1_bytes + nbr_bytes + w2p_bytes + w3p_bytes + posw_bytes + 64;
  if (ws_size < need) return;
  unsigned short* y1b = (unsigned short*)d_ws;
  int* nbr = (int*)((char*)d_ws + y1_bytes);
  unsigned short* w2p = (unsigned short*)((char*)d_ws + y1_bytes + nbr_bytes);
  unsigned short* w3p = w2p + 4096;
  float* posw = (float*)((char*)d_ws + y1_bytes + nbr_bytes + w2p_bytes + w3p_bytes);
  int* prog = (int*)((char*)posw + posw_bytes);

  // progress counters must be zero at kernel start on EVERY call/replay
  hipMemsetAsync(prog, 0, 64, stream);
  prep_kernel<<<1, 256, 0, stream>>>(W2, W3, w2p, w3p);
  fused_kernel<<<BB + NCONS, 256, 0, stream>>>(pos, x, W1, b1, pos_out,
                                               batch_out, y1b, posw, prog, nbr);
  mlp_kernel<<<BB * SS, 256, 0, stream>>>(pos, y1b, W1, b2, b3, w2p, w3p, nbr,
                                          pos_out, x_out);
}

// Round 8
// 1457.796 us; speedup vs baseline: 3.5994x; 3.5994x over previous
//
#include <hip/hip_runtime.h>
#include <cstdint>
#include <cstddef>

#define BB 8
#define NN 4096
#define FF 64
#define SS 2048
#define KK 64
#define H1c 64
#define H2c 64
#define H3c 128
#define R2 0.04f
#define CAP 448
#define NY1 240  // y1-role blocks in fused kernel; grid = 8+1+240 = 249 <= 256 CUs

typedef unsigned long long ull;
typedef __attribute__((ext_vector_type(4))) float f32x4;
typedef __attribute__((ext_vector_type(8))) short bf16x8;

// Exact (numpy-order, non-fma) squared distance: (dx*dx + dy*dy) + dz*dz
__device__ __forceinline__ float d2_exact(float ax, float ay, float az,
                                          float bx, float by, float bz) {
  float dx = __fsub_rn(ax, bx);
  float dy = __fsub_rn(ay, by);
  float dz = __fsub_rn(az, bz);
  return __fadd_rn(__fadd_rn(__fmul_rn(dx, dx), __fmul_rn(dy, dy)), __fmul_rn(dz, dz));
}

// round-to-nearest-even float -> bf16 bits
__device__ __forceinline__ unsigned short f2bf(float f) {
  unsigned u = __float_as_uint(f);
  return (unsigned short)((u + 0x7fffu + ((u >> 16) & 1u)) >> 16);
}

#define WAVE_MAX_DPP(v)                                                        \
  do {                                                                         \
    v = max(v, __builtin_amdgcn_update_dpp(0, v, 0x111, 0xf, 0xf, true));      \
    v = max(v, __builtin_amdgcn_update_dpp(0, v, 0x112, 0xf, 0xf, true));      \
    v = max(v, __builtin_amdgcn_update_dpp(0, v, 0x114, 0xf, 0xf, true));      \
    v = max(v, __builtin_amdgcn_update_dpp(0, v, 0x118, 0xf, 0xf, true));      \
    v = max(v, __builtin_amdgcn_update_dpp(0, v, 0x142, 0xf, 0xf, true));      \
    v = max(v, __builtin_amdgcn_update_dpp(0, v, 0x143, 0xf, 0xf, true));      \
  } while (0)

// ---------------- Kernel 1: fused FPS (blocks 0-7, exclusive CUs) -----------
// + weight-prep (block 8) + y1 GEMM (blocks 9..248). Grid 249 <= 256 CUs so
// every block gets a private CU; fps issue slots are never shared.
__global__ __launch_bounds__(256) void fused_kernel(
    const float* __restrict__ pos, const float* __restrict__ x,
    const float* __restrict__ W1, const float* __restrict__ b1,
    const float* __restrict__ W2, const float* __restrict__ W3,
    float* __restrict__ pos_out, float* __restrict__ batch_out,
    unsigned short* __restrict__ y1b, unsigned short* __restrict__ w2p,
    unsigned short* __restrict__ w3p) {
  __shared__ __align__(16) char smem[49152];
  __shared__ ull skey[2][4];
  const int tid = threadIdx.x;

  if (blockIdx.x < BB) {
    // ================= FPS role (R1-proven structure, 1253 us) ============
    float* plds = (float*)smem;
    const int b = blockIdx.x;
    const float4* src = (const float4*)(pos + (size_t)b * NN * 3);
    float4* dstl = (float4*)plds;
#pragma unroll
    for (int k = 0; k < 12; ++k) dstl[tid + k * 256] = src[tid + k * 256];
    __syncthreads();

    float px[16], py[16], pz[16], dmin[16];
#pragma unroll
    for (int i = 0; i < 16; ++i) {
      int p = tid * 16 + i;
      px[i] = plds[p * 3 + 0];
      py[i] = plds[p * 3 + 1];
      pz[i] = plds[p * 3 + 2];
      dmin[i] = INFINITY;
    }
    const int lane = tid & 63, wv = tid >> 6;
    float cx = plds[0], cy = plds[1], cz = plds[2];

    for (int s = 0; s < SS; ++s) {
      if (tid == 0) {
        int o = b * SS + s;
        pos_out[o * 3 + 0] = cx;
        pos_out[o * 3 + 1] = cy;
        pos_out[o * 3 + 2] = cz;
      }
      ull kk[16];
#pragma unroll
      for (int i = 0; i < 16; ++i) {
        float d = d2_exact(px[i], py[i], pz[i], cx, cy, cz);
        dmin[i] = fminf(dmin[i], d);
        kk[i] = ((ull)__float_as_uint(dmin[i]) << 32) | (unsigned)(~(tid * 16 + i));
      }
#pragma unroll
      for (int st = 1; st < 16; st <<= 1)
#pragma unroll
        for (int i = 0; i < 16; i += 2 * st)
          if (kk[i + st] > kk[i]) kk[i] = kk[i + st];
      const ull best = kk[0];

      const int hi = (int)(unsigned)(best >> 32);
      int v = hi;
      WAVE_MAX_DPP(v);
      const int wmax = __builtin_amdgcn_readlane(v, 63);
      const ull bal = __ballot(hi == wmax);
      const int wl = (int)__builtin_ctzll(bal);
      const unsigned klo =
          (unsigned)__builtin_amdgcn_readlane((int)(unsigned)best, wl);
      const int buf = s & 1;
      if (lane == 0) skey[buf][wv] = ((ull)(unsigned)wmax << 32) | klo;
      __syncthreads();

      const ull k0 = skey[buf][0], k1 = skey[buf][1];
      const ull k2 = skey[buf][2], k3 = skey[buf][3];
      ull ka = k0 > k1 ? k0 : k1;
      const ull kb2 = k2 > k3 ? k2 : k3;
      if (kb2 > ka) ka = kb2;
      const int cur = (int)(~(unsigned)(ka & 0xffffffffu));
      cx = plds[cur * 3 + 0];
      cy = plds[cur * 3 + 1];
      cz = plds[cur * 3 + 2];
    }
    for (int i = tid; i < SS; i += 256) batch_out[b * SS + i] = (float)b;
    return;
  }

  if (blockIdx.x == BB) {
    // ================= prep role: pack W2/W3 into MFMA B-fragment order ====
    for (int e = tid; e < 4096; e += 256) {
      int j = e & 7, l = (e >> 3) & 63, s = (e >> 9) & 1, c = e >> 10;
      w2p[e] = f2bf(W2[(s * 32 + 8 * (l >> 4) + j) * H2c + c * 16 + (l & 15)]);
    }
    for (int e = tid; e < 8192; e += 256) {
      int j = e & 7, l = (e >> 3) & 63, s = (e >> 9) & 1, c = e >> 10;
      w3p[e] = f2bf(W3[(s * 32 + 8 * (l >> 4) + j) * H3c + c * 16 + (l & 15)]);
    }
    return;
  }

  // ================= y1 role: y1 = x @ W1[0:64,:] + b1 -> bf16 =============
  float(*xs)[65] = (float(*)[65])smem;
  const int cid = blockIdx.x - BB - 1;  // 0..239
  for (int t = cid; t < 512; t += NY1) {
    const int r0 = t * 64;
    const float4* src = (const float4*)(x + (size_t)r0 * FF);
#pragma unroll
    for (int q = 0; q < 4; q++) {
      int p = tid + q * 256;
      float4 v = src[p];
      int row = (p * 4) >> 6, col = (p * 4) & 63;
      xs[row][col + 0] = v.x;
      xs[row][col + 1] = v.y;
      xs[row][col + 2] = v.z;
      xs[row][col + 3] = v.w;
    }
    __syncthreads();
    const int c4 = (tid & 15) * 4, kb = (tid >> 4) * 4;
    float acc[4][4];
#pragma unroll
    for (int kq = 0; kq < 4; kq++) {
      acc[kq][0] = b1[c4 + 0];
      acc[kq][1] = b1[c4 + 1];
      acc[kq][2] = b1[c4 + 2];
      acc[kq][3] = b1[c4 + 3];
    }
    for (int f = 0; f < FF; ++f) {
      float4 w = *(const float4*)(W1 + f * H1c + c4);
#pragma unroll
      for (int kq = 0; kq < 4; kq++) {
        float a = xs[kb + kq][f];
        acc[kq][0] += a * w.x;
        acc[kq][1] += a * w.y;
        acc[kq][2] += a * w.z;
        acc[kq][3] += a * w.w;
      }
    }
#pragma unroll
    for (int kq = 0; kq < 4; kq++) {
      ushort4 o;
      o.x = f2bf(acc[kq][0]);
      o.y = f2bf(acc[kq][1]);
      o.z = f2bf(acc[kq][2]);
      o.w = f2bf(acc[kq][3]);
      *(ushort4*)(y1b + (size_t)(r0 + kb + kq) * H1c + c4) = o;
    }
    __syncthreads();
  }
}

// ---------------- Kernel 2: ball query with rank-based parallel select ------
// Per wave-task: scan 4096 pts -> compacted keys (d2bits<<32|idx) in LDS;
// if M>64, each lane ranks its 7 candidates against all M via broadcast
// ds_read_b64 (no serial extraction); rank<64 writes its unique nbr slot.
__global__ __launch_bounds__(256) void ballq_kernel(const float* __restrict__ pos,
                                                    const float* __restrict__ pos_out,
                                                    int* __restrict__ nbr) {
  __shared__ float plds[NN * 3];
  __shared__ __align__(16) ull kc[4][CAP];
  const int tid = threadIdx.x;
  const int b = blockIdx.x >> 6;
  const int chunk = blockIdx.x & 63;
  const float4* src = (const float4*)(pos + (size_t)b * NN * 3);
  float4* dstl = (float4*)plds;
#pragma unroll
  for (int k = 0; k < 12; k++) dstl[tid + k * 256] = src[tid + k * 256];
  __syncthreads();

  const int w = tid >> 6, lane = tid & 63;
  for (int t8 = 0; t8 < 8; ++t8) {
    const int s = chunk * 32 + w * 8 + t8;
    const int g = b * SS + s;
    const float cx = pos_out[g * 3 + 0], cy = pos_out[g * 3 + 1], cz = pos_out[g * 3 + 2];
    int cnt = 0;
    for (int t = 0; t < 64; ++t) {
      int j = t * 64 + lane;
      float d2 = d2_exact(plds[j * 3 + 0], plds[j * 3 + 1], plds[j * 3 + 2], cx, cy, cz);
      bool pred = (d2 <= R2);
      unsigned long long mask = __ballot(pred);
      if (pred) {
        int p = cnt + __popcll(mask & ((1ull << lane) - 1ull));
        if (p < CAP) kc[w][p] = ((ull)__float_as_uint(d2) << 32) | (unsigned)j;
      }
      cnt += (int)__popcll(mask);
    }
    int M = cnt < CAP ? cnt : CAP;
    __syncthreads();  // wave-local lists ready (also isolates reuse per t8)

    if (M <= 64) {
      int v = (lane < M) ? (b * NN + (int)(unsigned)(kc[w][lane] & 0xffffffffu)) : -1;
      nbr[(size_t)g * KK + lane] = v;
    } else {
      ull mk[7];
      int rk[7];
#pragma unroll
      for (int q = 0; q < 7; q++) {
        int p = lane + q * 64;
        mk[q] = (p < M) ? kc[w][p] : ~0ull;
        rk[q] = 0;
      }
      int i = 0;
      for (; i + 2 <= M; i += 2) {
        ull ka = kc[w][i], kb2 = kc[w][i + 1];
#pragma unroll
        for (int q = 0; q < 7; q++)
          rk[q] += (int)(ka < mk[q]) + (int)(kb2 < mk[q]);
      }
      if (i < M) {
        ull ka = kc[w][i];
#pragma unroll
        for (int q = 0; q < 7; q++) rk[q] += (int)(ka < mk[q]);
      }
#pragma unroll
      for (int q = 0; q < 7; q++) {
        int p = lane + q * 64;
        if (p < M && rk[q] < KK)
          nbr[(size_t)g * KK + rk[q]] = b * NN + (int)(unsigned)(mk[q] & 0xffffffffu);
      }
    }
    __syncthreads();
  }
}

// ---------------- Kernel 3: MFMA MLP, 4 centroids per block -----------------
__global__ __launch_bounds__(256) void mlp_kernel(
    const float* __restrict__ pos, const unsigned short* __restrict__ y1b,
    const float* __restrict__ W1, const float* __restrict__ b2,
    const float* __restrict__ b3, const unsigned short* __restrict__ w2p,
    const unsigned short* __restrict__ w3p, const int* __restrict__ nbr,
    const float* __restrict__ pos_out, float* __restrict__ x_out) {
  __shared__ __align__(16) unsigned short lw2[4096];
  __shared__ __align__(16) unsigned short lw3[8192];
  __shared__ float w1r[3][64];
  __shared__ int nl[64];
  __shared__ float red[4][128];
  __shared__ __align__(16) unsigned short h2t[4][16][88];
  const int tid = threadIdx.x;
  const int lane = tid & 63, wv = tid >> 6;
  const int lrow = lane & 15, g16 = lane >> 4;

  {
    const uint4* s2 = (const uint4*)w2p;
    uint4* d2v = (uint4*)lw2;
    for (int i = tid; i < 512; i += 256) d2v[i] = s2[i];
    const uint4* s3 = (const uint4*)w3p;
    uint4* d3v = (uint4*)lw3;
    for (int i = tid; i < 1024; i += 256) d3v[i] = s3[i];
    if (tid < 192) w1r[tid / 64][tid % 64] = W1[(64 + tid / 64) * H1c + (tid % 64)];
  }
  const bf16x8* w2f = (const bf16x8*)lw2;
  const bf16x8* w3f = (const bf16x8*)lw3;

  for (int pass = 0; pass < 4; ++pass) {
    const int g = blockIdx.x * 4 + pass;
    if (tid < 64) nl[tid] = nbr[(size_t)g * KK + tid];
    const float cx = pos_out[g * 3 + 0], cy = pos_out[g * 3 + 1],
                cz = pos_out[g * 3 + 2];
    __syncthreads();  // nl + (pass 0) weights visible; prior-pass LDS retired

    const int r = wv * 16 + lrow;
    const int j = nl[r];

    bf16x8 a0 = (bf16x8)0, a1 = (bf16x8)0;
    if (j >= 0) {
      const float rx = pos[j * 3 + 0] - cx;
      const float ry = pos[j * 3 + 1] - cy;
      const float rz = pos[j * 3 + 2] - cz;
      const unsigned short* yr = y1b + (size_t)j * H1c;
      uint4 vlo = *(const uint4*)(yr + 8 * g16);
      uint4 vhi = *(const uint4*)(yr + 32 + 8 * g16);
      const unsigned* plo = (const unsigned*)&vlo;
      const unsigned* phi = (const unsigned*)&vhi;
#pragma unroll
      for (int q = 0; q < 4; ++q) {
        unsigned u = plo[q];
        int k0 = 8 * g16 + 2 * q;
        float e0 = __uint_as_float(u << 16) + rx * w1r[0][k0] + ry * w1r[1][k0] +
                   rz * w1r[2][k0];
        float e1 = __uint_as_float(u & 0xffff0000u) + rx * w1r[0][k0 + 1] +
                   ry * w1r[1][k0 + 1] + rz * w1r[2][k0 + 1];
        a0[2 * q] = (short)f2bf(fmaxf(e0, 0.f));
        a0[2 * q + 1] = (short)f2bf(fmaxf(e1, 0.f));
        unsigned u2 = phi[q];
        int k1 = 32 + k0;
        float f0 = __uint_as_float(u2 << 16) + rx * w1r[0][k1] + ry * w1r[1][k1] +
                   rz * w1r[2][k1];
        float f1 = __uint_as_float(u2 & 0xffff0000u) + rx * w1r[0][k1 + 1] +
                   ry * w1r[1][k1 + 1] + rz * w1r[2][k1 + 1];
        a1[2 * q] = (short)f2bf(fmaxf(f0, 0.f));
        a1[2 * q + 1] = (short)f2bf(fmaxf(f1, 0.f));
      }
    }

#pragma unroll
    for (int c = 0; c < 4; ++c) {
      float bb = b2[c * 16 + lrow];
      f32x4 acc = {bb, bb, bb, bb};
      acc = __builtin_amdgcn_mfma_f32_16x16x32_bf16(a0, w2f[(c * 2 + 0) * 64 + lane], acc, 0, 0, 0);
      acc = __builtin_amdgcn_mfma_f32_16x16x32_bf16(a1, w2f[(c * 2 + 1) * 64 + lane], acc, 0, 0, 0);
#pragma unroll
      for (int t = 0; t < 4; ++t)
        h2t[wv][4 * g16 + t][c * 16 + lrow] = f2bf(fmaxf(acc[t], 0.f));
    }

    bf16x8 a20 = *(const bf16x8*)&h2t[wv][lrow][8 * g16];
    bf16x8 a21 = *(const bf16x8*)&h2t[wv][lrow][32 + 8 * g16];

    float vmax[8];
#pragma unroll
    for (int c = 0; c < 8; ++c) {
      float bb = b3[c * 16 + lrow];
      f32x4 acc = {bb, bb, bb, bb};
      acc = __builtin_amdgcn_mfma_f32_16x16x32_bf16(a20, w3f[(c * 2 + 0) * 64 + lane], acc, 0, 0, 0);
      acc = __builtin_amdgcn_mfma_f32_16x16x32_bf16(a21, w3f[(c * 2 + 1) * 64 + lane], acc, 0, 0, 0);
      float m = -INFINITY;
#pragma unroll
      for (int t = 0; t < 4; ++t) {
        int rg = wv * 16 + 4 * g16 + t;
        float val = (nl[rg] >= 0) ? fmaxf(acc[t], 0.f) : -INFINITY;
        m = fmaxf(m, val);
      }
      m = fmaxf(m, __shfl_xor(m, 16));
      m = fmaxf(m, __shfl_xor(m, 32));
      vmax[c] = m;
    }
    if (g16 == 0) {
#pragma unroll
      for (int c = 0; c < 8; ++c) red[wv][c * 16 + lrow] = vmax[c];
    }
    __syncthreads();
    if (tid < H3c) {
      float m = fmaxf(fmaxf(red[0][tid], red[1][tid]), fmaxf(red[2][tid], red[3][tid]));
      x_out[(size_t)g * H3c + tid] = m;
    }
  }
}

extern "C" void kernel_launch(void* const* d_in, const int* in_sizes, int n_in,
                              void* d_out, int out_size, void* d_ws, size_t ws_size,
                              hipStream_t stream) {
  const float* x = (const float*)d_in[0];
  const float* pos = (const float*)d_in[1];
  // d_in[2] = batch (int32) unused: clouds are equal-size by construction
  const float* W1 = (const float*)d_in[3];
  const float* b1 = (const float*)d_in[4];
  const float* W2 = (const float*)d_in[5];
  const float* b2 = (const float*)d_in[6];
  const float* W3 = (const float*)d_in[7];
  const float* b3 = (const float*)d_in[8];

  float* out = (float*)d_out;
  float* x_out = out;                                // [B*S, 128]
  float* pos_out = out + (size_t)BB * SS * H3c;      // [B*S, 3]
  float* batch_out = pos_out + (size_t)BB * SS * 3;  // [B*S]

  const size_t y1_bytes = (size_t)BB * NN * H1c * sizeof(unsigned short);  // 4 MB
  const size_t nbr_bytes = (size_t)BB * SS * KK * sizeof(int);             // 4 MB
  const size_t w2p_bytes = 4096 * sizeof(unsigned short);
  const size_t w3p_bytes = 8192 * sizeof(unsigned short);
  if (ws_size < y1_bytes + nbr_bytes + w2p_bytes + w3p_bytes) return;
  unsigned short* y1b = (unsigned short*)d_ws;
  int* nbr = (int*)((char*)d_ws + y1_bytes);
  unsigned short* w2p = (unsigned short*)((char*)d_ws + y1_bytes + nbr_bytes);
  unsigned short* w3p = w2p + 4096;

  fused_kernel<<<BB + 1 + NY1, 256, 0, stream>>>(pos, x, W1, b1, W2, W3,
                                                 pos_out, batch_out, y1b, w2p, w3p);
  ballq_kernel<<<BB * 64, 256, 0, stream>>>(pos, pos_out, nbr);
  mlp_kernel<<<BB * SS / 4, 256, 0, stream>>>(pos, y1b, W1, b2, b3, w2p, w3p,
                                              nbr, pos_out, x_out);
}

// Round 9
// 1377.257 us; speedup vs baseline: 3.8099x; 1.0585x over previous
//
#include <hip/hip_runtime.h>
#include <cstdint>
#include <cstddef>

#define BB 8
#define NN 4096
#define FF 64
#define SS 2048
#define KK 64
#define H1c 64
#define H2c 64
#define H3c 128
#define R2 0.04f
#define CAP 448
#define NY1 240  // y1-role blocks; grid = 8+1+240 = 249 <= 256 CUs

typedef unsigned long long ull;
typedef __attribute__((ext_vector_type(4))) float f32x4;
typedef __attribute__((ext_vector_type(8))) short bf16x8;

// Exact (numpy-order, non-fma) squared distance: (dx*dx + dy*dy) + dz*dz
__device__ __forceinline__ float d2_exact(float ax, float ay, float az,
                                          float bx, float by, float bz) {
  float dx = __fsub_rn(ax, bx);
  float dy = __fsub_rn(ay, by);
  float dz = __fsub_rn(az, bz);
  return __fadd_rn(__fadd_rn(__fmul_rn(dx, dx), __fmul_rn(dy, dy)), __fmul_rn(dz, dz));
}

// round-to-nearest-even float -> bf16 bits
__device__ __forceinline__ unsigned short f2bf(float f) {
  unsigned u = __float_as_uint(f);
  return (unsigned short)((u + 0x7fffu + ((u >> 16) & 1u)) >> 16);
}

#define WAVE_MAX_DPP(v)                                                        \
  do {                                                                         \
    v = max(v, __builtin_amdgcn_update_dpp(0, v, 0x111, 0xf, 0xf, true));      \
    v = max(v, __builtin_amdgcn_update_dpp(0, v, 0x112, 0xf, 0xf, true));      \
    v = max(v, __builtin_amdgcn_update_dpp(0, v, 0x114, 0xf, 0xf, true));      \
    v = max(v, __builtin_amdgcn_update_dpp(0, v, 0x118, 0xf, 0xf, true));      \
    v = max(v, __builtin_amdgcn_update_dpp(0, v, 0x142, 0xf, 0xf, true));      \
    v = max(v, __builtin_amdgcn_update_dpp(0, v, 0x143, 0xf, 0xf, true));      \
  } while (0)

// ---------------- Kernel 1: fused FPS (blocks 0-7) + prep (8) + y1 (9..248) -
// FPS: 512 threads, 8 contiguous points/thread. Per step: d2+fmin update,
// float max3 value tree, uniform descending index scan (first-occurrence),
// DPP wave value-max, ballot+ctz -> winner lane, readlane(lidx) -> wave key
// (value<<32 | ~idx), single barrier, 8-key tournament, broadcast gather.
__global__ __launch_bounds__(512) void fused_kernel(
    const float* __restrict__ pos, const float* __restrict__ x,
    const float* __restrict__ W1, const float* __restrict__ b1,
    const float* __restrict__ W2, const float* __restrict__ W3,
    float* __restrict__ pos_out, float* __restrict__ batch_out,
    unsigned short* __restrict__ y1b, unsigned short* __restrict__ w2p,
    unsigned short* __restrict__ w3p) {
  __shared__ __align__(16) char smem[49152];
  __shared__ ull skey[2][8];
  const int tid = threadIdx.x;

  if (blockIdx.x < BB) {
    // ================= FPS role =================
    float* plds = (float*)smem;
    const int b = blockIdx.x;
    const float4* src = (const float4*)(pos + (size_t)b * NN * 3);
    float4* dstl = (float4*)plds;
#pragma unroll
    for (int k = 0; k < 6; ++k) dstl[tid + k * 512] = src[tid + k * 512];
    __syncthreads();

    float px[8], py[8], pz[8], dmin[8];
#pragma unroll
    for (int i = 0; i < 8; ++i) {
      int p = tid * 8 + i;
      px[i] = plds[p * 3 + 0];
      py[i] = plds[p * 3 + 1];
      pz[i] = plds[p * 3 + 2];
      dmin[i] = INFINITY;
    }
    const int lane = tid & 63, wv = tid >> 6;
    float cx = plds[0], cy = plds[1], cz = plds[2];

    for (int s = 0; s < SS; ++s) {
      if (tid == 0) {
        int o = b * SS + s;
        pos_out[o * 3 + 0] = cx;
        pos_out[o * 3 + 1] = cy;
        pos_out[o * 3 + 2] = cz;
      }
#pragma unroll
      for (int i = 0; i < 8; ++i) {
        float d = d2_exact(px[i], py[i], pz[i], cx, cy, cz);
        dmin[i] = fminf(dmin[i], d);
      }
      // local value max (float; all values non-negative or +inf)
      float m0 = fmaxf(fmaxf(dmin[0], dmin[1]), fmaxf(dmin[2], dmin[3]));
      float m1 = fmaxf(fmaxf(dmin[4], dmin[5]), fmaxf(dmin[6], dmin[7]));
      const float lmax = fmaxf(m0, m1);
      // uniform descending scan -> first-occurrence local index
      int lidx = 0;
#pragma unroll
      for (int i = 7; i >= 0; --i)
        if (__float_as_int(dmin[i]) == __float_as_int(lmax)) lidx = i;

      // wave value max via DPP (bit-int max exact for non-negative floats)
      const int lv = __float_as_int(lmax);
      int v = lv;
      WAVE_MAX_DPP(v);
      const int wmax = __builtin_amdgcn_readlane(v, 63);
      const ull bal = __ballot(lv == wmax);
      const int wl = (int)__builtin_ctzll(bal);
      const int wli = __builtin_amdgcn_readlane(lidx, wl);
      const int widx = ((wv << 6) + wl) * 8 + wli;
      const int buf = s & 1;
      if (lane == 0)
        skey[buf][wv] = ((ull)(unsigned)wmax << 32) | (unsigned)(~widx);
      __syncthreads();

      ull ka = skey[buf][0];
#pragma unroll
      for (int q = 1; q < 8; ++q) {
        ull kq = skey[buf][q];
        if (kq > ka) ka = kq;
      }
      const int cur = (int)(~(unsigned)(ka & 0xffffffffu));
      cx = plds[cur * 3 + 0];
      cy = plds[cur * 3 + 1];
      cz = plds[cur * 3 + 2];
    }
    for (int i = tid; i < SS; i += 512) batch_out[b * SS + i] = (float)b;
    return;
  }

  if (blockIdx.x == BB) {
    // ================= prep role: pack W2/W3 into MFMA B-fragment order ====
    for (int e = tid; e < 4096; e += 512) {
      int j = e & 7, l = (e >> 3) & 63, s = (e >> 9) & 1, c = e >> 10;
      w2p[e] = f2bf(W2[(s * 32 + 8 * (l >> 4) + j) * H2c + c * 16 + (l & 15)]);
    }
    for (int e = tid; e < 8192; e += 512) {
      int j = e & 7, l = (e >> 3) & 63, s = (e >> 9) & 1, c = e >> 10;
      w3p[e] = f2bf(W3[(s * 32 + 8 * (l >> 4) + j) * H3c + c * 16 + (l & 15)]);
    }
    return;
  }

  // ================= y1 role: y1 = x @ W1[0:64,:] + b1 -> bf16 =============
  float(*xs)[65] = (float(*)[65])smem;
  const int cid = blockIdx.x - BB - 1;  // 0..239
  for (int t = cid; t < 512; t += NY1) {
    const int r0 = t * 64;
    const float4* src = (const float4*)(x + (size_t)r0 * FF);
#pragma unroll
    for (int q = 0; q < 2; q++) {
      int p = tid + q * 512;
      float4 v = src[p];
      int row = (p * 4) >> 6, col = (p * 4) & 63;
      xs[row][col + 0] = v.x;
      xs[row][col + 1] = v.y;
      xs[row][col + 2] = v.z;
      xs[row][col + 3] = v.w;
    }
    __syncthreads();
    const int c4 = (tid & 15) * 4, kb = (tid >> 4) * 2;
    float acc[2][4];
#pragma unroll
    for (int kq = 0; kq < 2; kq++) {
      acc[kq][0] = b1[c4 + 0];
      acc[kq][1] = b1[c4 + 1];
      acc[kq][2] = b1[c4 + 2];
      acc[kq][3] = b1[c4 + 3];
    }
    for (int f = 0; f < FF; ++f) {
      float4 w = *(const float4*)(W1 + f * H1c + c4);
#pragma unroll
      for (int kq = 0; kq < 2; kq++) {
        float a = xs[kb + kq][f];
        acc[kq][0] += a * w.x;
        acc[kq][1] += a * w.y;
        acc[kq][2] += a * w.z;
        acc[kq][3] += a * w.w;
      }
    }
#pragma unroll
    for (int kq = 0; kq < 2; kq++) {
      ushort4 o;
      o.x = f2bf(acc[kq][0]);
      o.y = f2bf(acc[kq][1]);
      o.z = f2bf(acc[kq][2]);
      o.w = f2bf(acc[kq][3]);
      *(ushort4*)(y1b + (size_t)(r0 + kb + kq) * H1c + c4) = o;
    }
    __syncthreads();
  }
}

// ---------------- Kernel 2: ball query with rank-based parallel select ------
__global__ __launch_bounds__(256) void ballq_kernel(const float* __restrict__ pos,
                                                    const float* __restrict__ pos_out,
                                                    int* __restrict__ nbr) {
  __shared__ float plds[NN * 3];
  __shared__ __align__(16) ull kc[4][CAP];
  const int tid = threadIdx.x;
  const int b = blockIdx.x >> 6;
  const int chunk = blockIdx.x & 63;
  const float4* src = (const float4*)(pos + (size_t)b * NN * 3);
  float4* dstl = (float4*)plds;
#pragma unroll
  for (int k = 0; k < 12; k++) dstl[tid + k * 256] = src[tid + k * 256];
  __syncthreads();

  const int w = tid >> 6, lane = tid & 63;
  for (int t8 = 0; t8 < 8; ++t8) {
    const int s = chunk * 32 + w * 8 + t8;
    const int g = b * SS + s;
    const float cx = pos_out[g * 3 + 0], cy = pos_out[g * 3 + 1], cz = pos_out[g * 3 + 2];
    int cnt = 0;
    for (int t = 0; t < 64; ++t) {
      int j = t * 64 + lane;
      float d2 = d2_exact(plds[j * 3 + 0], plds[j * 3 + 1], plds[j * 3 + 2], cx, cy, cz);
      bool pred = (d2 <= R2);
      unsigned long long mask = __ballot(pred);
      if (pred) {
        int p = cnt + __popcll(mask & ((1ull << lane) - 1ull));
        if (p < CAP) kc[w][p] = ((ull)__float_as_uint(d2) << 32) | (unsigned)j;
      }
      cnt += (int)__popcll(mask);
    }
    int M = cnt < CAP ? cnt : CAP;
    __syncthreads();

    if (M <= 64) {
      int v = (lane < M) ? (b * NN + (int)(unsigned)(kc[w][lane] & 0xffffffffu)) : -1;
      nbr[(size_t)g * KK + lane] = v;
    } else {
      ull mk[7];
      int rk[7];
#pragma unroll
      for (int q = 0; q < 7; q++) {
        int p = lane + q * 64;
        mk[q] = (p < M) ? kc[w][p] : ~0ull;
        rk[q] = 0;
      }
      int i = 0;
      for (; i + 2 <= M; i += 2) {
        ull ka = kc[w][i], kb2 = kc[w][i + 1];
#pragma unroll
        for (int q = 0; q < 7; q++)
          rk[q] += (int)(ka < mk[q]) + (int)(kb2 < mk[q]);
      }
      if (i < M) {
        ull ka = kc[w][i];
#pragma unroll
        for (int q = 0; q < 7; q++) rk[q] += (int)(ka < mk[q]);
      }
#pragma unroll
      for (int q = 0; q < 7; q++) {
        int p = lane + q * 64;
        if (p < M && rk[q] < KK)
          nbr[(size_t)g * KK + rk[q]] = b * NN + (int)(unsigned)(mk[q] & 0xffffffffu);
      }
    }
    __syncthreads();
  }
}

// ---------------- Kernel 3: MFMA MLP, 4 centroids per block -----------------
__global__ __launch_bounds__(256) void mlp_kernel(
    const float* __restrict__ pos, const unsigned short* __restrict__ y1b,
    const float* __restrict__ W1, const float* __restrict__ b2,
    const float* __restrict__ b3, const unsigned short* __restrict__ w2p,
    const unsigned short* __restrict__ w3p, const int* __restrict__ nbr,
    const float* __restrict__ pos_out, float* __restrict__ x_out) {
  __shared__ __align__(16) unsigned short lw2[4096];
  __shared__ __align__(16) unsigned short lw3[8192];
  __shared__ float w1r[3][64];
  __shared__ int nl[64];
  __shared__ float red[4][128];
  __shared__ __align__(16) unsigned short h2t[4][16][88];
  const int tid = threadIdx.x;
  const int lane = tid & 63, wv = tid >> 6;
  const int lrow = lane & 15, g16 = lane >> 4;

  {
    const uint4* s2 = (const uint4*)w2p;
    uint4* d2v = (uint4*)lw2;
    for (int i = tid; i < 512; i += 256) d2v[i] = s2[i];
    const uint4* s3 = (const uint4*)w3p;
    uint4* d3v = (uint4*)lw3;
    for (int i = tid; i < 1024; i += 256) d3v[i] = s3[i];
    if (tid < 192) w1r[tid / 64][tid % 64] = W1[(64 + tid / 64) * H1c + (tid % 64)];
  }
  const bf16x8* w2f = (const bf16x8*)lw2;
  const bf16x8* w3f = (const bf16x8*)lw3;

  for (int pass = 0; pass < 4; ++pass) {
    const int g = blockIdx.x * 4 + pass;
    if (tid < 64) nl[tid] = nbr[(size_t)g * KK + tid];
    const float cx = pos_out[g * 3 + 0], cy = pos_out[g * 3 + 1],
                cz = pos_out[g * 3 + 2];
    __syncthreads();

    const int r = wv * 16 + lrow;
    const int j = nl[r];

    bf16x8 a0 = (bf16x8)0, a1 = (bf16x8)0;
    if (j >= 0) {
      const float rx = pos[j * 3 + 0] - cx;
      const float ry = pos[j * 3 + 1] - cy;
      const float rz = pos[j * 3 + 2] - cz;
      const unsigned short* yr = y1b + (size_t)j * H1c;
      uint4 vlo = *(const uint4*)(yr + 8 * g16);
      uint4 vhi = *(const uint4*)(yr + 32 + 8 * g16);
      const unsigned* plo = (const unsigned*)&vlo;
      const unsigned* phi = (const unsigned*)&vhi;
#pragma unroll
      for (int q = 0; q < 4; ++q) {
        unsigned u = plo[q];
        int k0 = 8 * g16 + 2 * q;
        float e0 = __uint_as_float(u << 16) + rx * w1r[0][k0] + ry * w1r[1][k0] +
                   rz * w1r[2][k0];
        float e1 = __uint_as_float(u & 0xffff0000u) + rx * w1r[0][k0 + 1] +
                   ry * w1r[1][k0 + 1] + rz * w1r[2][k0 + 1];
        a0[2 * q] = (short)f2bf(fmaxf(e0, 0.f));
        a0[2 * q + 1] = (short)f2bf(fmaxf(e1, 0.f));
        unsigned u2 = phi[q];
        int k1 = 32 + k0;
        float f0 = __uint_as_float(u2 << 16) + rx * w1r[0][k1] + ry * w1r[1][k1] +
                   rz * w1r[2][k1];
        float f1 = __uint_as_float(u2 & 0xffff0000u) + rx * w1r[0][k1 + 1] +
                   ry * w1r[1][k1 + 1] + rz * w1r[2][k1 + 1];
        a1[2 * q] = (short)f2bf(fmaxf(f0, 0.f));
        a1[2 * q + 1] = (short)f2bf(fmaxf(f1, 0.f));
      }
    }

#pragma unroll
    for (int c = 0; c < 4; ++c) {
      float bb = b2[c * 16 + lrow];
      f32x4 acc = {bb, bb, bb, bb};
      acc = __builtin_amdgcn_mfma_f32_16x16x32_bf16(a0, w2f[(c * 2 + 0) * 64 + lane], acc, 0, 0, 0);
      acc = __builtin_amdgcn_mfma_f32_16x16x32_bf16(a1, w2f[(c * 2 + 1) * 64 + lane], acc, 0, 0, 0);
#pragma unroll
      for (int t = 0; t < 4; ++t)
        h2t[wv][4 * g16 + t][c * 16 + lrow] = f2bf(fmaxf(acc[t], 0.f));
    }

    bf16x8 a20 = *(const bf16x8*)&h2t[wv][lrow][8 * g16];
    bf16x8 a21 = *(const bf16x8*)&h2t[wv][lrow][32 + 8 * g16];

    float vmax[8];
#pragma unroll
    for (int c = 0; c < 8; ++c) {
      float bb = b3[c * 16 + lrow];
      f32x4 acc = {bb, bb, bb, bb};
      acc = __builtin_amdgcn_mfma_f32_16x16x32_bf16(a20, w3f[(c * 2 + 0) * 64 + lane], acc, 0, 0, 0);
      acc = __builtin_amdgcn_mfma_f32_16x16x32_bf16(a21, w3f[(c * 2 + 1) * 64 + lane], acc, 0, 0, 0);
      float m = -INFINITY;
#pragma unroll
      for (int t = 0; t < 4; ++t) {
        int rg = wv * 16 + 4 * g16 + t;
        float val = (nl[rg] >= 0) ? fmaxf(acc[t], 0.f) : -INFINITY;
        m = fmaxf(m, val);
      }
      m = fmaxf(m, __shfl_xor(m, 16));
      m = fmaxf(m, __shfl_xor(m, 32));
      vmax[c] = m;
    }
    if (g16 == 0) {
#pragma unroll
      for (int c = 0; c < 8; ++c) red[wv][c * 16 + lrow] = vmax[c];
    }
    __syncthreads();
    if (tid < H3c) {
      float m = fmaxf(fmaxf(red[0][tid], red[1][tid]), fmaxf(red[2][tid], red[3][tid]));
      x_out[(size_t)g * H3c + tid] = m;
    }
  }
}

extern "C" void kernel_launch(void* const* d_in, const int* in_sizes, int n_in,
                              void* d_out, int out_size, void* d_ws, size_t ws_size,
                              hipStream_t stream) {
  const float* x = (const float*)d_in[0];
  const float* pos = (const float*)d_in[1];
  // d_in[2] = batch (int32) unused: clouds are equal-size by construction
  const float* W1 = (const float*)d_in[3];
  const float* b1 = (const float*)d_in[4];
  const float* W2 = (const float*)d_in[5];
  const float* b2 = (const float*)d_in[6];
  const float* W3 = (const float*)d_in[7];
  const float* b3 = (const float*)d_in[8];

  float* out = (float*)d_out;
  float* x_out = out;                                // [B*S, 128]
  float* pos_out = out + (size_t)BB * SS * H3c;      // [B*S, 3]
  float* batch_out = pos_out + (size_t)BB * SS * 3;  // [B*S]

  const size_t y1_bytes = (size_t)BB * NN * H1c * sizeof(unsigned short);  // 4 MB
  const size_t nbr_bytes = (size_t)BB * SS * KK * sizeof(int);             // 4 MB
  const size_t w2p_bytes = 4096 * sizeof(unsigned short);
  const size_t w3p_bytes = 8192 * sizeof(unsigned short);
  if (ws_size < y1_bytes + nbr_bytes + w2p_bytes + w3p_bytes) return;
  unsigned short* y1b = (unsigned short*)d_ws;
  int* nbr = (int*)((char*)d_ws + y1_bytes);
  unsigned short* w2p = (unsigned short*)((char*)d_ws + y1_bytes + nbr_bytes);
  unsigned short* w3p = w2p + 4096;

  fused_kernel<<<BB + 1 + NY1, 512, 0, stream>>>(pos, x, W1, b1, W2, W3,
                                                 pos_out, batch_out, y1b, w2p, w3p);
  ballq_kernel<<<BB * 64, 256, 0, stream>>>(pos, pos_out, nbr);
  mlp_kernel<<<BB * SS / 4, 256, 0, stream>>>(pos, y1b, W1, b2, b3, w2p, w3p,
                                              nbr, pos_out, x_out);
}